// Round 7
// baseline (244.028 us; speedup 1.0000x reference)
//
#include <hip/hip_runtime.h>
#include <hip/hip_bf16.h>

#define N_NODES 100000
#define N_EDGES 800000
#define CAP     64
#define NTILES  ((N_NODES + 63) / 64)   // 1563

typedef unsigned short u16;
typedef unsigned int   u32;
typedef __attribute__((ext_vector_type(8))) short bf16x8;
typedef __attribute__((ext_vector_type(4))) float f32x4;

__device__ inline u32 pack_bf2(float a, float b) {
    __hip_bfloat16 ha = __float2bfloat16(a), hb = __float2bfloat16(b);
    u16 ua, ub;
    __builtin_memcpy(&ua, &ha, 2);
    __builtin_memcpy(&ub, &hb, 2);
    return (u32)ua | ((u32)ub << 16);
}
__device__ inline u16 to_bf16(float a) {
    __hip_bfloat16 h = __float2bfloat16(a);
    u16 u; __builtin_memcpy(&u, &h, 2);
    return u;
}
__device__ inline void unpk(u32 w, float& a, float& b) {
    a = __uint_as_float(w << 16);
    b = __uint_as_float(w & 0xffff0000u);
}

// ---------------- Kernel 0: weight prep (transpose + bf16) ----------------
// WcatT[n][kk]: n 0-127 WqT, 128-255 WkT, 256-383 WvT, 384-511 WffnT
// WoT[n][kk] = Wo[kk][n]
__global__ __launch_bounds__(256) void prep_weights(
    const float* __restrict__ Wq, const float* __restrict__ Wk,
    const float* __restrict__ Wv, const float* __restrict__ Wf,
    const float* __restrict__ Wo, u16* __restrict__ WcatT, u16* __restrict__ WoT)
{
    int idx = blockIdx.x * 256 + threadIdx.x;
    if (idx < 512 * 128) {
        int n = idx >> 7, kk = idx & 127;
        const float* W = (n < 128) ? Wq : (n < 256) ? Wk : (n < 384) ? Wv : Wf;
        WcatT[idx] = to_bf16(W[kk * 128 + (n & 127)]);
    } else if (idx < 512 * 128 + 128 * 128) {
        int i2 = idx - 512 * 128;
        int n = i2 >> 7, kk = i2 & 127;
        WoT[i2] = to_bf16(Wo[kk * 128 + n]);
    }
}

// ---------------- Kernel 1: q/k/v projections via MFMA, no LDS ------------
// 1563 blocks x 384 thr (6 waves), one 64-row tile per block. Wave owns
// 64 rows x 64 cols. W frags in VGPRs; A frags loaded straight from global
// (2x dwordx4 per frag) and packed in-register -> no LDS, no barriers.
// Swapped-operand MFMA -> lane holds 4 consecutive out cols -> 8B stores.
__global__ __launch_bounds__(384, 3) void proj_mfma(
    const float* __restrict__ feats, const u16* __restrict__ WT,
    const float* __restrict__ bq, const float* __restrict__ bk,
    const float* __restrict__ bv,
    u16* __restrict__ q, u16* __restrict__ k, u16* __restrict__ v)
{
    const int tid = threadIdx.x;
    const int wid = tid >> 6, l = tid & 63;
    const int q4 = l >> 4, c16 = l & 15;
    const int colg0 = wid * 64;

    // cache weight fragments: wfr[ks][nt] = WT[col=colg0+nt*16+c16][ks*32+q4*8 ..+7]
    bf16x8 wfr[4][4];
    #pragma unroll
    for (int ks = 0; ks < 4; ++ks)
        #pragma unroll
        for (int nt = 0; nt < 4; ++nt)
            wfr[ks][nt] = *reinterpret_cast<const bf16x8*>(
                WT + (size_t)(colg0 + nt * 16 + c16) * 128 + ks * 32 + q4 * 8);

    const float* bias_src = (wid < 2) ? bq : (wid < 4) ? bk : bv;
    u16* outb = (wid < 2) ? q : (wid < 4) ? k : v;
    const int cbase = colg0 - (wid >> 1) * 128;    // col within target [0,128)

    const int row0 = blockIdx.x * 64;
    // this lane's 4 A-rows (clamped for the tail tile; stores are masked)
    const float* arow[4];
    #pragma unroll
    for (int mt = 0; mt < 4; ++mt) {
        int gr = row0 + mt * 16 + c16;
        arow[mt] = feats + (size_t)(gr < N_NODES ? gr : N_NODES - 1) * 128;
    }

    f32x4 acc[4][4];    // [mt = 16-row group][nt = 16-col group]
    #pragma unroll
    for (int a = 0; a < 4; ++a)
        #pragma unroll
        for (int b = 0; b < 4; ++b)
            acc[a][b] = (f32x4){0.f,0.f,0.f,0.f};

    #pragma unroll
    for (int ks = 0; ks < 4; ++ks) {
        const int col = ks * 32 + q4 * 8;
        bf16x8 afr[4];
        #pragma unroll
        for (int mt = 0; mt < 4; ++mt) {
            const float4* p = reinterpret_cast<const float4*>(arow[mt] + col);
            float4 f0 = p[0], f1 = p[1];
            u32 u0 = pack_bf2(f0.x, f0.y), u1 = pack_bf2(f0.z, f0.w);
            u32 u2 = pack_bf2(f1.x, f1.y), u3 = pack_bf2(f1.z, f1.w);
            uint4 pk; pk.x=u0; pk.y=u1; pk.z=u2; pk.w=u3;
            afr[mt] = *reinterpret_cast<bf16x8*>(&pk);
        }
        // swapped operands: D^T fragment -> lane l, reg j =
        //   C[row = mt*16 + (l&15)][col = nt*16 + (l>>4)*4 + j]
        #pragma unroll
        for (int mt = 0; mt < 4; ++mt)
            #pragma unroll
            for (int nt = 0; nt < 4; ++nt)
                acc[mt][nt] = __builtin_amdgcn_mfma_f32_16x16x32_bf16(
                    wfr[ks][nt], afr[mt], acc[mt][nt], 0, 0, 0);
    }

    // packed 8B stores: 16 per thread
    #pragma unroll
    for (int nt = 0; nt < 4; ++nt) {
        const int c = cbase + nt * 16 + q4 * 4;
        float4 b4 = *reinterpret_cast<const float4*>(bias_src + c);
        #pragma unroll
        for (int mt = 0; mt < 4; ++mt) {
            int gr = row0 + mt * 16 + c16;
            if (gr < N_NODES) {
                uint2 pk;
                pk.x = pack_bf2(acc[mt][nt][0] + b4.x, acc[mt][nt][1] + b4.y);
                pk.y = pack_bf2(acc[mt][nt][2] + b4.z, acc[mt][nt][3] + b4.w);
                *reinterpret_cast<uint2*>(outb + (size_t)gr * 128 + c) = pk;
            }
        }
    }
}

// ---------------- Kernel 2: bucket build (stores SRC id, not edge id) -----
__global__ __launch_bounds__(256) void bucket_kernel(
    const int* __restrict__ esrc, const int* __restrict__ edst,
    int* __restrict__ cnt, int* __restrict__ bucket)
{
    int e = blockIdx.x * 256 + threadIdx.x;
    if (e >= N_EDGES) return;
    int d = edst[e];
    int pos = atomicAdd(&cnt[d], 1);
    if (pos < CAP) bucket[(size_t)d * CAP + pos] = esrc[e];
}

// ---------------- Kernel 3: fused score + aggregate -----------------------
// wave per node; 8-lane group per edge (8 edges in flight); lane = head.
__global__ __launch_bounds__(256) void agg_fused(
    const u16* __restrict__ q, const u16* __restrict__ k, const u16* __restrict__ v,
    const int* __restrict__ cnt, const int* __restrict__ bucket,
    u16* __restrict__ wv)
{
    const int wid  = threadIdx.x >> 6;
    const int lane = threadIdx.x & 63;
    const int node = blockIdx.x * 4 + wid;
    int deg = cnt[node]; if (deg > CAP) deg = CAP;

    const int grp = lane >> 3;   // edge slot within iteration (0..7)
    const int el  = lane & 7;    // head index

    // q fragment for this lane's head, prescaled by 1/sqrt(128)
    const float scale = 0.08838834764831845f;
    const uint4* qp = reinterpret_cast<const uint4*>(q + (size_t)node * 128 + el * 16);
    uint4 q0 = qp[0], q1 = qp[1];
    float qf[16];
    {
        u32 qw[8] = {q0.x,q0.y,q0.z,q0.w,q1.x,q1.y,q1.z,q1.w};
        #pragma unroll
        for (int j = 0; j < 8; ++j) {
            float a, b; unpk(qw[j], a, b);
            qf[2*j] = a * scale; qf[2*j+1] = b * scale;
        }
    }

    // preload all src ids: lane i holds bucket[node][i]
    int srcs = (lane < deg) ? bucket[(size_t)node * CAP + lane] : 0;

    float acc[16];
    #pragma unroll
    for (int j = 0; j < 16; ++j) acc[j] = 0.f;
    float z = 0.f;

    const int nIter = (deg + 7) >> 3;
    for (int it = 0; it < nIter; ++it) {
        int i = it * 8 + grp;
        bool valid = (i < deg);
        int s = __shfl(srcs, i);
        const uint4* kp = reinterpret_cast<const uint4*>(k + (size_t)s * 128 + el * 16);
        uint4 k0 = kp[0], k1 = kp[1];
        const uint4* vp = reinterpret_cast<const uint4*>(v + (size_t)s * 128 + el * 16);
        uint4 v0 = vp[0], v1 = vp[1];

        u32 kw[8] = {k0.x,k0.y,k0.z,k0.w,k1.x,k1.y,k1.z,k1.w};
        float p = 0.f;
        #pragma unroll
        for (int j = 0; j < 8; ++j) {
            float a, b; unpk(kw[j], a, b);
            p = fmaf(a, qf[2*j], p);
            p = fmaf(b, qf[2*j+1], p);
        }
        p = fminf(fmaxf(p, -5.f), 5.f);
        float sc = valid ? __expf(p) : 0.f;

        u32 vw[8] = {v0.x,v0.y,v0.z,v0.w,v1.x,v1.y,v1.z,v1.w};
        #pragma unroll
        for (int j = 0; j < 8; ++j) {
            float a, b; unpk(vw[j], a, b);
            acc[2*j]   = fmaf(a, sc, acc[2*j]);
            acc[2*j+1] = fmaf(b, sc, acc[2*j+1]);
        }
        z += sc;
    }

    // reduce across the 8 edge-groups (lanes with equal el)
    #pragma unroll
    for (int mask = 8; mask <= 32; mask <<= 1) {
        #pragma unroll
        for (int j = 0; j < 16; ++j) acc[j] += __shfl_xor(acc[j], mask);
        z += __shfl_xor(z, mask);
    }

    if (grp == 0) {   // lanes 0..7: head el writes dims el*16..el*16+15
        float inv = 1.f / z;
        uint4 w0, w1;
        w0.x = pack_bf2(acc[0]*inv,  acc[1]*inv);
        w0.y = pack_bf2(acc[2]*inv,  acc[3]*inv);
        w0.z = pack_bf2(acc[4]*inv,  acc[5]*inv);
        w0.w = pack_bf2(acc[6]*inv,  acc[7]*inv);
        w1.x = pack_bf2(acc[8]*inv,  acc[9]*inv);
        w1.y = pack_bf2(acc[10]*inv, acc[11]*inv);
        w1.z = pack_bf2(acc[12]*inv, acc[13]*inv);
        w1.w = pack_bf2(acc[14]*inv, acc[15]*inv);
        uint4* wp = reinterpret_cast<uint4*>(wv + (size_t)node * 128 + el * 16);
        wp[0] = w0; wp[1] = w1;
    }
}

// ---------------- Kernel 4: h0 = feats@Wffn; o = wv@Wo; h = h0+o+biases; --
//                  out = h + LN(h). block 256 thr, tile 64 rows.
__global__ __launch_bounds__(256) void out_mfma(
    const float* __restrict__ feats, const u16* __restrict__ wv,
    const u16* __restrict__ WoT, const u16* __restrict__ WcatT,
    const float* __restrict__ bo, const float* __restrict__ bffn,
    const float* __restrict__ lg, const float* __restrict__ lb,
    float* __restrict__ out)
{
    __shared__ __align__(16) char smem[2 * 64 * 136 * sizeof(u16)];
    u16 (*Awv)[136] = reinterpret_cast<u16(*)[136]>(smem);
    u16 (*Aft)[136] = reinterpret_cast<u16(*)[136]>(smem + 64 * 136 * sizeof(u16));
    float (*Hs)[132] = reinterpret_cast<float(*)[132]>(smem);   // reused later

    const int tid  = threadIdx.x;
    const int row0 = blockIdx.x * 64;
    const u16* WfT = WcatT + 384 * 128;

    // stage wv (bf16 copy) and feats (fp32 -> bf16)
    #pragma unroll
    for (int i = 0; i < 4; ++i) {
        int idx = tid + i * 256;
        int r = idx >> 4, c8 = (idx & 15) * 8;
        int gr = row0 + r; if (gr >= N_NODES) gr = N_NODES - 1;
        *reinterpret_cast<uint4*>(&Awv[r][c8]) =
            *reinterpret_cast<const uint4*>(wv + (size_t)gr * 128 + c8);
        const float4* p = reinterpret_cast<const float4*>(feats + (size_t)gr * 128 + c8);
        float4 f0 = p[0], f1 = p[1];
        uint4 pk;
        pk.x = pack_bf2(f0.x, f0.y); pk.y = pack_bf2(f0.z, f0.w);
        pk.z = pack_bf2(f1.x, f1.y); pk.w = pack_bf2(f1.z, f1.w);
        *reinterpret_cast<uint4*>(&Aft[r][c8]) = pk;
    }
    __syncthreads();

    const int wid = tid >> 6, l = tid & 63;
    const int q4 = l >> 4, c16 = l & 15;
    const int col0 = wid * 32;

    f32x4 acc[4][2];
    #pragma unroll
    for (int a = 0; a < 4; ++a) { acc[a][0] = (f32x4){0.f,0.f,0.f,0.f}; acc[a][1] = acc[a][0]; }

    #pragma unroll
    for (int ks = 0; ks < 4; ++ks) {
        const int k0 = ks * 32 + q4 * 8;
        bf16x8 afr[4], bfr[2];
        #pragma unroll
        for (int mt = 0; mt < 4; ++mt)
            afr[mt] = *reinterpret_cast<const bf16x8*>(&Awv[mt * 16 + c16][k0]);
        #pragma unroll
        for (int nt = 0; nt < 2; ++nt)
            bfr[nt] = *reinterpret_cast<const bf16x8*>(WoT + (size_t)(col0 + nt * 16 + c16) * 128 + k0);
        #pragma unroll
        for (int mt = 0; mt < 4; ++mt)
            #pragma unroll
            for (int nt = 0; nt < 2; ++nt)
                acc[mt][nt] = __builtin_amdgcn_mfma_f32_16x16x32_bf16(afr[mt], bfr[nt], acc[mt][nt], 0, 0, 0);
    }
    #pragma unroll
    for (int ks = 0; ks < 4; ++ks) {
        const int k0 = ks * 32 + q4 * 8;
        bf16x8 afr[4], bfr[2];
        #pragma unroll
        for (int mt = 0; mt < 4; ++mt)
            afr[mt] = *reinterpret_cast<const bf16x8*>(&Aft[mt * 16 + c16][k0]);
        #pragma unroll
        for (int nt = 0; nt < 2; ++nt)
            bfr[nt] = *reinterpret_cast<const bf16x8*>(WfT + (size_t)(col0 + nt * 16 + c16) * 128 + k0);
        #pragma unroll
        for (int mt = 0; mt < 4; ++mt)
            #pragma unroll
            for (int nt = 0; nt < 2; ++nt)
                acc[mt][nt] = __builtin_amdgcn_mfma_f32_16x16x32_bf16(afr[mt], bfr[nt], acc[mt][nt], 0, 0, 0);
    }
    __syncthreads();    // done reading Awv/Aft; smem becomes Hs

    #pragma unroll
    for (int nt = 0; nt < 2; ++nt) {
        const int col = col0 + nt * 16 + c16;
        const float bias = bo[col] + bffn[col];
        #pragma unroll
        for (int mt = 0; mt < 4; ++mt) {
            #pragma unroll
            for (int j = 0; j < 4; ++j) {
                int r = mt * 16 + q4 * 4 + j;
                Hs[r][col] = acc[mt][nt][j] + bias;
            }
        }
    }
    __syncthreads();

    // LayerNorm: 4 threads per row
    const int r   = tid >> 2;
    const int sub = tid & 3;
    float sum = 0.f, sq = 0.f;
    #pragma unroll
    for (int jj = 0; jj < 8; ++jj) {
        float4 x = *reinterpret_cast<const float4*>(&Hs[r][(sub + jj * 4) * 4]);
        sum += x.x + x.y + x.z + x.w;
        sq  += x.x*x.x + x.y*x.y + x.z*x.z + x.w*x.w;
    }
    sum += __shfl_xor(sum, 1); sq += __shfl_xor(sq, 1);
    sum += __shfl_xor(sum, 2); sq += __shfl_xor(sq, 2);
    float mu   = sum * (1.f / 128.f);
    float var  = sq * (1.f / 128.f) - mu * mu;
    float rsig = rsqrtf(var + 1e-5f);

    int gr = row0 + r;
    if (gr < N_NODES) {
        #pragma unroll
        for (int jj = 0; jj < 8; ++jj) {
            int c = (sub + jj * 4) * 4;
            float4 x = *reinterpret_cast<const float4*>(&Hs[r][c]);
            float4 g = *reinterpret_cast<const float4*>(lg + c);
            float4 b = *reinterpret_cast<const float4*>(lb + c);
            float4 o;
            o.x = x.x + (x.x - mu) * rsig * g.x + b.x;
            o.y = x.y + (x.y - mu) * rsig * g.y + b.y;
            o.z = x.z + (x.z - mu) * rsig * g.z + b.z;
            o.w = x.w + (x.w - mu) * rsig * g.w + b.w;
            *reinterpret_cast<float4*>(out + (size_t)gr * 128 + c) = o;
        }
    }
}

// ---------------- launch ---------------------------------------------------
extern "C" void kernel_launch(void* const* d_in, const int* in_sizes, int n_in,
                              void* d_out, int out_size, void* d_ws, size_t ws_size,
                              hipStream_t stream) {
    const float* feats = (const float*)d_in[0];
    const int*   esrc  = (const int*)d_in[1];
    const int*   edst  = (const int*)d_in[2];
    const float* Wq = (const float*)d_in[3];  const float* bq = (const float*)d_in[4];
    const float* Wk = (const float*)d_in[5];  const float* bk = (const float*)d_in[6];
    const float* Wv = (const float*)d_in[7];  const float* bv = (const float*)d_in[8];
    const float* Wo = (const float*)d_in[9];  const float* bo = (const float*)d_in[10];
    const float* Wf = (const float*)d_in[11]; const float* bf = (const float*)d_in[12];
    const float* lg = (const float*)d_in[13]; const float* lb = (const float*)d_in[14];
    float* out = (float*)d_out;

    char* ws = (char*)d_ws;
    const size_t NB = (size_t)N_NODES * 128 * sizeof(u16);     // 25.6 MB
    u16* q     = (u16*)(ws);
    u16* k     = (u16*)(ws + NB);
    u16* v     = (u16*)(ws + 2 * NB);
    u16* wv    = (u16*)(ws + 3 * NB);
    u16* WcatT = (u16*)(ws + 4 * NB);
    u16* WoT   = (u16*)(ws + 4 * NB + 512 * 128 * sizeof(u16));
    int* cnt   = (int*)(ws + 4 * NB + (512 * 128 + 128 * 128) * sizeof(u16));
    int* bucket= (int*)(ws + 4 * NB + (512 * 128 + 128 * 128) * sizeof(u16)
                             + (size_t)N_NODES * sizeof(int));

    hipMemsetAsync(cnt, 0, (size_t)N_NODES * sizeof(int), stream);

    prep_weights<<<320, 256, 0, stream>>>(Wq, Wk, Wv, Wf, Wo, WcatT, WoT);
    proj_mfma<<<NTILES, 384, 0, stream>>>(feats, WcatT, bq, bk, bv, q, k, v);
    bucket_kernel<<<(N_EDGES + 255) / 256, 256, 0, stream>>>(esrc, edst, cnt, bucket);
    agg_fused<<<N_NODES / 4, 256, 0, stream>>>(q, k, v, cnt, bucket, wv);
    out_mfma<<<(N_NODES + 63) / 64, 256, 0, stream>>>(feats, wv, WoT, WcatT,
                                                      bo, bf, lg, lb, out);
}

// Round 8
// 195.191 us; speedup vs baseline: 1.2502x; 1.2502x over previous
//
#include <hip/hip_runtime.h>
#include <hip/hip_bf16.h>

#define N_NODES 100000
#define N_EDGES 800000
#define CAP     64
#define NTILES  ((N_NODES + 63) / 64)   // 1563
#define PROJ_BLOCKS 1042

typedef unsigned short u16;
typedef unsigned int   u32;
typedef __attribute__((ext_vector_type(8))) short bf16x8;
typedef __attribute__((ext_vector_type(4))) float f32x4;

__device__ inline u32 pack_bf2(float a, float b) {
    __hip_bfloat16 ha = __float2bfloat16(a), hb = __float2bfloat16(b);
    u16 ua, ub;
    __builtin_memcpy(&ua, &ha, 2);
    __builtin_memcpy(&ub, &hb, 2);
    return (u32)ua | ((u32)ub << 16);
}
__device__ inline u16 to_bf16(float a) {
    __hip_bfloat16 h = __float2bfloat16(a);
    u16 u; __builtin_memcpy(&u, &h, 2);
    return u;
}
__device__ inline void unpk(u32 w, float& a, float& b) {
    a = __uint_as_float(w << 16);
    b = __uint_as_float(w & 0xffff0000u);
}

// ---------------- Kernel 0: weight prep (transpose + bf16) ----------------
__global__ __launch_bounds__(256) void prep_weights(
    const float* __restrict__ Wq, const float* __restrict__ Wk,
    const float* __restrict__ Wv, const float* __restrict__ Wf,
    const float* __restrict__ Wo, u16* __restrict__ WcatT, u16* __restrict__ WoT)
{
    int idx = blockIdx.x * 256 + threadIdx.x;
    if (idx < 512 * 128) {
        int n = idx >> 7, kk = idx & 127;
        const float* W = (n < 128) ? Wq : (n < 256) ? Wk : (n < 384) ? Wv : Wf;
        WcatT[idx] = to_bf16(W[kk * 128 + (n & 127)]);
    } else if (idx < 512 * 128 + 128 * 128) {
        int i2 = idx - 512 * 128;
        int n = i2 >> 7, kk = i2 & 127;
        WoT[i2] = to_bf16(Wo[kk * 128 + n]);
    }
}

// ---------------- Kernel 1: q/k/v projections via MFMA + bucket build -----
// 1042 blocks x 384 thr (6 waves); grid-stride over 64-row tiles (1-2 each).
// Wave owns 64 rows x 64 cols. W frags cached in VGPRs; feats staged in LDS.
// Swapped-operand MFMA -> lane holds 4 consecutive out cols -> 8B stores.
// Tail: grid-stride edge loop builds the reverse-CSR buckets (int atomics),
// overlapping with other blocks' GEMM phases.
__global__ __launch_bounds__(384, 3) void proj_mfma(
    const float* __restrict__ feats, const u16* __restrict__ WT,
    const float* __restrict__ bq, const float* __restrict__ bk,
    const float* __restrict__ bv,
    u16* __restrict__ q, u16* __restrict__ k, u16* __restrict__ v,
    const int* __restrict__ esrc, const int* __restrict__ edst,
    int* __restrict__ cnt, int* __restrict__ bucket)
{
    __shared__ __align__(16) u16 As[64][136];
    const int tid = threadIdx.x;
    const int wid = tid >> 6, l = tid & 63;
    const int q4 = l >> 4, c16 = l & 15;
    const int colg0 = wid * 64;

    // cache weight fragments: wfr[ks][nt] = WT[col=colg0+nt*16+c16][ks*32+q4*8 ..+7]
    bf16x8 wfr[4][4];
    #pragma unroll
    for (int ks = 0; ks < 4; ++ks)
        #pragma unroll
        for (int nt = 0; nt < 4; ++nt)
            wfr[ks][nt] = *reinterpret_cast<const bf16x8*>(
                WT + (size_t)(colg0 + nt * 16 + c16) * 128 + ks * 32 + q4 * 8);

    const float* bias_src = (wid < 2) ? bq : (wid < 4) ? bk : bv;
    u16* outb = (wid < 2) ? q : (wid < 4) ? k : v;
    const int cbase = colg0 - (wid >> 1) * 128;    // col within target [0,128)

    for (int tile = blockIdx.x; tile < NTILES; tile += gridDim.x) {
        const int row0 = tile * 64;

        // stage + convert feats tile: 64 rows x 128 cols (1024 8-elem tasks)
        #pragma unroll
        for (int i = 0; i < 3; ++i) {
            int idx = tid + i * 384;
            if (idx < 1024) {
                int r = idx >> 4, c8 = (idx & 15) * 8;
                int gr = row0 + r;
                float4 f0, f1;
                if (gr < N_NODES) {
                    const float4* p = reinterpret_cast<const float4*>(feats + (size_t)gr * 128 + c8);
                    f0 = p[0]; f1 = p[1];
                } else {
                    f0 = make_float4(0.f,0.f,0.f,0.f); f1 = f0;
                }
                uint4 pk;
                pk.x = pack_bf2(f0.x, f0.y); pk.y = pack_bf2(f0.z, f0.w);
                pk.z = pack_bf2(f1.x, f1.y); pk.w = pack_bf2(f1.z, f1.w);
                *reinterpret_cast<uint4*>(&As[r][c8]) = pk;
            }
        }
        __syncthreads();

        f32x4 acc[4][4];    // [mt = 16-row group][nt = 16-col group]
        #pragma unroll
        for (int a = 0; a < 4; ++a)
            #pragma unroll
            for (int b = 0; b < 4; ++b)
                acc[a][b] = (f32x4){0.f,0.f,0.f,0.f};

        #pragma unroll
        for (int ks = 0; ks < 4; ++ks) {
            const int k0 = ks * 32 + q4 * 8;
            bf16x8 afr[4];
            #pragma unroll
            for (int mt = 0; mt < 4; ++mt)
                afr[mt] = *reinterpret_cast<const bf16x8*>(&As[mt * 16 + c16][k0]);
            // swapped operands: D^T fragment -> lane l, reg j =
            //   C[row = mt*16 + (l&15)][col = nt*16 + (l>>4)*4 + j]
            #pragma unroll
            for (int mt = 0; mt < 4; ++mt)
                #pragma unroll
                for (int nt = 0; nt < 4; ++nt)
                    acc[mt][nt] = __builtin_amdgcn_mfma_f32_16x16x32_bf16(
                        wfr[ks][nt], afr[mt], acc[mt][nt], 0, 0, 0);
        }

        // packed 8B stores: 16 per thread
        #pragma unroll
        for (int nt = 0; nt < 4; ++nt) {
            const int c = cbase + nt * 16 + q4 * 4;
            float4 b4 = *reinterpret_cast<const float4*>(bias_src + c);
            #pragma unroll
            for (int mt = 0; mt < 4; ++mt) {
                int gr = row0 + mt * 16 + c16;
                if (gr < N_NODES) {
                    uint2 pk;
                    pk.x = pack_bf2(acc[mt][nt][0] + b4.x, acc[mt][nt][1] + b4.y);
                    pk.y = pack_bf2(acc[mt][nt][2] + b4.z, acc[mt][nt][3] + b4.w);
                    *reinterpret_cast<uint2*>(outb + (size_t)gr * 128 + c) = pk;
                }
            }
        }
        __syncthreads();
    }

    // fused bucket build (reverse CSR, stores SRC id)
    for (int e = blockIdx.x * 384 + tid; e < N_EDGES; e += gridDim.x * 384) {
        int d = edst[e];
        int pos = atomicAdd(&cnt[d], 1);
        if (pos < CAP) bucket[(size_t)d * CAP + pos] = esrc[e];
    }
}

// ---------------- Kernel 3: fused score + aggregate -----------------------
// wave per node; 8-lane group per edge (8 edges in flight); lane = head.
__global__ __launch_bounds__(256) void agg_fused(
    const u16* __restrict__ q, const u16* __restrict__ k, const u16* __restrict__ v,
    const int* __restrict__ cnt, const int* __restrict__ bucket,
    u16* __restrict__ wv)
{
    const int wid  = threadIdx.x >> 6;
    const int lane = threadIdx.x & 63;
    const int node = blockIdx.x * 4 + wid;
    int deg = cnt[node]; if (deg > CAP) deg = CAP;

    const int grp = lane >> 3;   // edge slot within iteration (0..7)
    const int el  = lane & 7;    // head index

    // q fragment for this lane's head, prescaled by 1/sqrt(128)
    const float scale = 0.08838834764831845f;
    const uint4* qp = reinterpret_cast<const uint4*>(q + (size_t)node * 128 + el * 16);
    uint4 q0 = qp[0], q1 = qp[1];
    float qf[16];
    {
        u32 qw[8] = {q0.x,q0.y,q0.z,q0.w,q1.x,q1.y,q1.z,q1.w};
        #pragma unroll
        for (int j = 0; j < 8; ++j) {
            float a, b; unpk(qw[j], a, b);
            qf[2*j] = a * scale; qf[2*j+1] = b * scale;
        }
    }

    // preload all src ids: lane i holds bucket[node][i]
    int srcs = (lane < deg) ? bucket[(size_t)node * CAP + lane] : 0;

    float acc[16];
    #pragma unroll
    for (int j = 0; j < 16; ++j) acc[j] = 0.f;
    float z = 0.f;

    const int nIter = (deg + 7) >> 3;
    for (int it = 0; it < nIter; ++it) {
        int i = it * 8 + grp;
        bool valid = (i < deg);
        int s = __shfl(srcs, i);
        const uint4* kp = reinterpret_cast<const uint4*>(k + (size_t)s * 128 + el * 16);
        uint4 k0 = kp[0], k1 = kp[1];
        const uint4* vp = reinterpret_cast<const uint4*>(v + (size_t)s * 128 + el * 16);
        uint4 v0 = vp[0], v1 = vp[1];

        u32 kw[8] = {k0.x,k0.y,k0.z,k0.w,k1.x,k1.y,k1.z,k1.w};
        float p = 0.f;
        #pragma unroll
        for (int j = 0; j < 8; ++j) {
            float a, b; unpk(kw[j], a, b);
            p = fmaf(a, qf[2*j], p);
            p = fmaf(b, qf[2*j+1], p);
        }
        p = fminf(fmaxf(p, -5.f), 5.f);
        float sc = valid ? __expf(p) : 0.f;

        u32 vw[8] = {v0.x,v0.y,v0.z,v0.w,v1.x,v1.y,v1.z,v1.w};
        #pragma unroll
        for (int j = 0; j < 8; ++j) {
            float a, b; unpk(vw[j], a, b);
            acc[2*j]   = fmaf(a, sc, acc[2*j]);
            acc[2*j+1] = fmaf(b, sc, acc[2*j+1]);
        }
        z += sc;
    }

    // reduce across the 8 edge-groups (lanes with equal el)
    #pragma unroll
    for (int mask = 8; mask <= 32; mask <<= 1) {
        #pragma unroll
        for (int j = 0; j < 16; ++j) acc[j] += __shfl_xor(acc[j], mask);
        z += __shfl_xor(z, mask);
    }

    if (grp == 0) {   // lanes 0..7: head el writes dims el*16..el*16+15
        float inv = 1.f / z;
        uint4 w0, w1;
        w0.x = pack_bf2(acc[0]*inv,  acc[1]*inv);
        w0.y = pack_bf2(acc[2]*inv,  acc[3]*inv);
        w0.z = pack_bf2(acc[4]*inv,  acc[5]*inv);
        w0.w = pack_bf2(acc[6]*inv,  acc[7]*inv);
        w1.x = pack_bf2(acc[8]*inv,  acc[9]*inv);
        w1.y = pack_bf2(acc[10]*inv, acc[11]*inv);
        w1.z = pack_bf2(acc[12]*inv, acc[13]*inv);
        w1.w = pack_bf2(acc[14]*inv, acc[15]*inv);
        uint4* wp = reinterpret_cast<uint4*>(wv + (size_t)node * 128 + el * 16);
        wp[0] = w0; wp[1] = w1;
    }
}

// ---------------- Kernel 4: h0 = feats@Wffn; o = wv@Wo; h = h0+o+biases; --
//                  out = h + LN(h). block 256 thr, tile 64 rows.
__global__ __launch_bounds__(256) void out_mfma(
    const float* __restrict__ feats, const u16* __restrict__ wv,
    const u16* __restrict__ WoT, const u16* __restrict__ WcatT,
    const float* __restrict__ bo, const float* __restrict__ bffn,
    const float* __restrict__ lg, const float* __restrict__ lb,
    float* __restrict__ out)
{
    __shared__ __align__(16) char smem[2 * 64 * 136 * sizeof(u16)];
    u16 (*Awv)[136] = reinterpret_cast<u16(*)[136]>(smem);
    u16 (*Aft)[136] = reinterpret_cast<u16(*)[136]>(smem + 64 * 136 * sizeof(u16));
    float (*Hs)[132] = reinterpret_cast<float(*)[132]>(smem);   // reused later
    float* muS = reinterpret_cast<float*>(smem + 64 * 132 * sizeof(float));
    float* rsS = muS + 64;   // fits: 33792 + 512 <= 34816

    const int tid  = threadIdx.x;
    const int row0 = blockIdx.x * 64;
    const u16* WfT = WcatT + 384 * 128;

    // stage wv (bf16 copy) and feats (fp32 -> bf16)
    #pragma unroll
    for (int i = 0; i < 4; ++i) {
        int idx = tid + i * 256;
        int r = idx >> 4, c8 = (idx & 15) * 8;
        int gr = row0 + r; if (gr >= N_NODES) gr = N_NODES - 1;
        *reinterpret_cast<uint4*>(&Awv[r][c8]) =
            *reinterpret_cast<const uint4*>(wv + (size_t)gr * 128 + c8);
        const float4* p = reinterpret_cast<const float4*>(feats + (size_t)gr * 128 + c8);
        float4 f0 = p[0], f1 = p[1];
        uint4 pk;
        pk.x = pack_bf2(f0.x, f0.y); pk.y = pack_bf2(f0.z, f0.w);
        pk.z = pack_bf2(f1.x, f1.y); pk.w = pack_bf2(f1.z, f1.w);
        *reinterpret_cast<uint4*>(&Aft[r][c8]) = pk;
    }
    __syncthreads();

    const int wid = tid >> 6, l = tid & 63;
    const int q4 = l >> 4, c16 = l & 15;
    const int col0 = wid * 32;

    f32x4 acc[4][2];
    #pragma unroll
    for (int a = 0; a < 4; ++a) { acc[a][0] = (f32x4){0.f,0.f,0.f,0.f}; acc[a][1] = acc[a][0]; }

    #pragma unroll
    for (int ks = 0; ks < 4; ++ks) {
        const int k0 = ks * 32 + q4 * 8;
        bf16x8 afr[4], bfr[2];
        #pragma unroll
        for (int mt = 0; mt < 4; ++mt)
            afr[mt] = *reinterpret_cast<const bf16x8*>(&Awv[mt * 16 + c16][k0]);
        #pragma unroll
        for (int nt = 0; nt < 2; ++nt)
            bfr[nt] = *reinterpret_cast<const bf16x8*>(WoT + (size_t)(col0 + nt * 16 + c16) * 128 + k0);
        #pragma unroll
        for (int mt = 0; mt < 4; ++mt)
            #pragma unroll
            for (int nt = 0; nt < 2; ++nt)
                acc[mt][nt] = __builtin_amdgcn_mfma_f32_16x16x32_bf16(afr[mt], bfr[nt], acc[mt][nt], 0, 0, 0);
    }
    #pragma unroll
    for (int ks = 0; ks < 4; ++ks) {
        const int k0 = ks * 32 + q4 * 8;
        bf16x8 afr[4], bfr[2];
        #pragma unroll
        for (int mt = 0; mt < 4; ++mt)
            afr[mt] = *reinterpret_cast<const bf16x8*>(&Aft[mt * 16 + c16][k0]);
        #pragma unroll
        for (int nt = 0; nt < 2; ++nt)
            bfr[nt] = *reinterpret_cast<const bf16x8*>(WfT + (size_t)(col0 + nt * 16 + c16) * 128 + k0);
        #pragma unroll
        for (int mt = 0; mt < 4; ++mt)
            #pragma unroll
            for (int nt = 0; nt < 2; ++nt)
                acc[mt][nt] = __builtin_amdgcn_mfma_f32_16x16x32_bf16(afr[mt], bfr[nt], acc[mt][nt], 0, 0, 0);
    }
    __syncthreads();    // done reading Awv/Aft; smem becomes Hs

    #pragma unroll
    for (int nt = 0; nt < 2; ++nt) {
        const int col = col0 + nt * 16 + c16;
        const float bias = bo[col] + bffn[col];
        #pragma unroll
        for (int mt = 0; mt < 4; ++mt) {
            #pragma unroll
            for (int j = 0; j < 4; ++j) {
                int r = mt * 16 + q4 * 4 + j;
                Hs[r][col] = acc[mt][nt][j] + bias;
            }
        }
    }
    __syncthreads();

    // LayerNorm stats: 4 threads per row
    {
        const int r   = tid >> 2;
        const int sub = tid & 3;
        float sum = 0.f, sq = 0.f;
        #pragma unroll
        for (int jj = 0; jj < 8; ++jj) {
            float4 x = *reinterpret_cast<const float4*>(&Hs[r][(sub + jj * 4) * 4]);
            sum += x.x + x.y + x.z + x.w;
            sq  += x.x*x.x + x.y*x.y + x.z*x.z + x.w*x.w;
        }
        sum += __shfl_xor(sum, 1); sq += __shfl_xor(sq, 1);
        sum += __shfl_xor(sum, 2); sq += __shfl_xor(sq, 2);
        float mu   = sum * (1.f / 128.f);
        float var  = sq * (1.f / 128.f) - mu * mu;
        if (sub == 0) { muS[r] = mu; rsS[r] = rsqrtf(var + 1e-5f); }
    }
    __syncthreads();

    // coalesced final store: wave writes 1KB contiguous
    #pragma unroll
    for (int i = 0; i < 8; ++i) {
        int idx = i * 256 + tid;
        int rr = idx >> 5, c4 = idx & 31;
        int gr = row0 + rr;
        if (gr < N_NODES) {
            float4 x = *reinterpret_cast<const float4*>(&Hs[rr][c4 * 4]);
            float4 g = *reinterpret_cast<const float4*>(lg + c4 * 4);
            float4 b = *reinterpret_cast<const float4*>(lb + c4 * 4);
            float m = muS[rr], rs = rsS[rr];
            float4 o;
            o.x = x.x + (x.x - m) * rs * g.x + b.x;
            o.y = x.y + (x.y - m) * rs * g.y + b.y;
            o.z = x.z + (x.z - m) * rs * g.z + b.z;
            o.w = x.w + (x.w - m) * rs * g.w + b.w;
            *reinterpret_cast<float4*>(out + (size_t)gr * 128 + c4 * 4) = o;
        }
    }
}

// ---------------- launch ---------------------------------------------------
extern "C" void kernel_launch(void* const* d_in, const int* in_sizes, int n_in,
                              void* d_out, int out_size, void* d_ws, size_t ws_size,
                              hipStream_t stream) {
    const float* feats = (const float*)d_in[0];
    const int*   esrc  = (const int*)d_in[1];
    const int*   edst  = (const int*)d_in[2];
    const float* Wq = (const float*)d_in[3];  const float* bq = (const float*)d_in[4];
    const float* Wk = (const float*)d_in[5];  const float* bk = (const float*)d_in[6];
    const float* Wv = (const float*)d_in[7];  const float* bv = (const float*)d_in[8];
    const float* Wo = (const float*)d_in[9];  const float* bo = (const float*)d_in[10];
    const float* Wf = (const float*)d_in[11]; const float* bf = (const float*)d_in[12];
    const float* lg = (const float*)d_in[13]; const float* lb = (const float*)d_in[14];
    float* out = (float*)d_out;

    char* ws = (char*)d_ws;
    const size_t NB = (size_t)N_NODES * 128 * sizeof(u16);     // 25.6 MB
    u16* q     = (u16*)(ws);
    u16* k     = (u16*)(ws + NB);
    u16* v     = (u16*)(ws + 2 * NB);
    u16* wv    = (u16*)(ws + 3 * NB);
    u16* WcatT = (u16*)(ws + 4 * NB);
    u16* WoT   = (u16*)(ws + 4 * NB + 512 * 128 * sizeof(u16));
    int* cnt   = (int*)(ws + 4 * NB + (512 * 128 + 128 * 128) * sizeof(u16));
    int* bucket= (int*)(ws + 4 * NB + (512 * 128 + 128 * 128) * sizeof(u16)
                             + (size_t)N_NODES * sizeof(int));

    hipMemsetAsync(cnt, 0, (size_t)N_NODES * sizeof(int), stream);

    prep_weights<<<320, 256, 0, stream>>>(Wq, Wk, Wv, Wf, Wo, WcatT, WoT);
    proj_mfma<<<PROJ_BLOCKS, 384, 0, stream>>>(feats, WcatT, bq, bk, bv, q, k, v,
                                               esrc, edst, cnt, bucket);
    agg_fused<<<N_NODES / 4, 256, 0, stream>>>(q, k, v, cnt, bucket, wv);
    out_mfma<<<(N_NODES + 63) / 64, 256, 0, stream>>>(feats, wv, WoT, WcatT,
                                                      bo, bf, lg, lb, out);
}